// Round 1
// baseline (2915.315 us; speedup 1.0000x reference)
//
#include <hip/hip_runtime.h>
#include <math.h>

#define NLINES 2048
#define WPL 32
#define EMBD 300
#define EMB_P 304      // padded stride for we rows (div by 4)
#define AD 400
#define NH 8
#define DPH 50
#define QKV_S 52       // padded stride for q/k/v rows in LDS
#define SC_S 36        // padded stride for score rows (word level)
#define BATCH 16
#define LPD 128        // lines per doc

__device__ __forceinline__ float elu(float x) {
    return x > 0.f ? x : expm1f(x);
}

#define SCALE 7.0710678118654755f   // sqrt(50)

// ---------------------------------------------------------------------------
// Kernel 1: fused word stage. One block per line (2048 blocks, 320 threads).
// Gather we=emb[d] -> LDS; per head: project q,k,v (elu) -> LDS; word
// attention + target attention folded:  line_e[h,d] = mask_l * sum_k cw[k]*v[k,d]
// where cw[k] = sum_j tw[j]*mask[j]*softmaxrow_j[k].
// ---------------------------------------------------------------------------
__launch_bounds__(320)
__global__ void word_kernel(const int* __restrict__ docs,
                            const float* __restrict__ emb,
                            const float* __restrict__ wq_w, const float* __restrict__ wq_b,
                            const float* __restrict__ wk_w, const float* __restrict__ wk_b,
                            const float* __restrict__ wv_w, const float* __restrict__ wv_b,
                            const float* __restrict__ w_tgt,
                            float* __restrict__ line_e, float* __restrict__ mask_l)
{
    __shared__ __align__(16) float we[WPL * EMB_P];       // 38912 B
    __shared__ float qkv[3 * WPL * QKV_S];                // 19968 B
    __shared__ float sc[WPL * SC_S];                      //  4608 B
    __shared__ float ts[WPL];
    __shared__ float tw[WPL];
    __shared__ float cw[WPL];
    __shared__ float msk[WPL];
    __shared__ float mls;

    const int tid = threadIdx.x;
    const int line = blockIdx.x;

    // word masks
    if (tid < WPL) {
        int tok = docs[line * WPL + tid];
        msk[tid] = (tok != 0) ? 1.f : 0.f;
    }
    __syncthreads();
    if (tid == 0) {
        float ml = 0.f;
        for (int w = 0; w < WPL; ++w) ml = fmaxf(ml, msk[w]);
        mls = ml;
        mask_l[line] = ml;
    }
    // gather embedding rows into LDS
    for (int idx = tid; idx < WPL * EMBD; idx += 320) {
        int w = idx / EMBD, e = idx - w * EMBD;
        int tok = docs[line * WPL + w];
        we[w * EMB_P + e] = emb[tok * EMBD + e];
    }
    __syncthreads();

    for (int h = 0; h < NH; ++h) {
        // ---- projection: q,k,v for this head (3 proj x 50 cols x 32 words)
        if (tid < 300) {
            int p = tid / 100;               // 0=q 1=k 2=v
            int r = tid - p * 100;
            int d = r >> 1;
            int wh = (r & 1) << 4;           // word half: 0 or 16
            int n = h * DPH + d;
            const float* Wp = (p == 0) ? wq_w : (p == 1) ? wk_w : wv_w;
            const float* Bp = (p == 0) ? wq_b : (p == 1) ? wk_b : wv_b;
            float acc[16];
            #pragma unroll
            for (int i = 0; i < 16; ++i) acc[i] = 0.f;
            for (int kk = 0; kk < EMBD / 4; ++kk) {
                float w0 = Wp[(4 * kk + 0) * AD + n];
                float w1 = Wp[(4 * kk + 1) * AD + n];
                float w2 = Wp[(4 * kk + 2) * AD + n];
                float w3 = Wp[(4 * kk + 3) * AD + n];
                #pragma unroll
                for (int i = 0; i < 16; ++i) {
                    const float4 e4 = *(const float4*)&we[(wh + i) * EMB_P + 4 * kk];
                    acc[i] += e4.x * w0 + e4.y * w1 + e4.z * w2 + e4.w * w3;
                }
            }
            float b = Bp[n];
            #pragma unroll
            for (int i = 0; i < 16; ++i)
                qkv[(p * WPL + wh + i) * QKV_S + d] = elu(acc[i] + b);
        }
        __syncthreads();

        // ---- scores (32x32) and target scores (32)
        if (tid < 256) {
            int j = tid >> 3;
            int kg = tid & 7;
            #pragma unroll
            for (int c = 0; c < 4; ++c) {
                int kk = kg * 4 + c;
                float s = 0.f;
                for (int dd = 0; dd < DPH; ++dd)
                    s += qkv[j * QKV_S + dd] * qkv[(WPL + kk) * QKV_S + dd];
                sc[j * SC_S + kk] = s / SCALE - 1e7f * (1.f - msk[kk]);
            }
        } else if (tid < 288) {
            int j = tid - 256;
            float s = 0.f;
            for (int dd = 0; dd < DPH; ++dd)
                s += w_tgt[h * DPH + dd] * qkv[(WPL + j) * QKV_S + dd];
            ts[j] = s / SCALE - 1e7f * (1.f - msk[j]);
        }
        __syncthreads();

        // ---- row softmax + target softmax
        if (tid < WPL) {
            int j = tid;
            float m = -1e30f;
            for (int kk = 0; kk < WPL; ++kk) m = fmaxf(m, sc[j * SC_S + kk]);
            float sum = 0.f;
            for (int kk = 0; kk < WPL; ++kk) {
                float e = expf(sc[j * SC_S + kk] - m);
                sc[j * SC_S + kk] = e;
                sum += e;
            }
            float inv = 1.f / sum;
            for (int kk = 0; kk < WPL; ++kk) sc[j * SC_S + kk] *= inv;
        } else if (tid == WPL) {
            float m = -1e30f;
            for (int j = 0; j < WPL; ++j) m = fmaxf(m, ts[j]);
            float sum = 0.f;
            for (int j = 0; j < WPL; ++j) { float e = expf(ts[j] - m); tw[j] = e; sum += e; }
            float inv = 1.f / sum;
            for (int j = 0; j < WPL; ++j) tw[j] *= inv;
        }
        __syncthreads();

        // ---- combined weights cw[k] = sum_j tw[j]*msk[j]*w1[j][k]
        if (tid < WPL) {
            int kk = tid;
            float c = 0.f;
            for (int j = 0; j < WPL; ++j)
                c += tw[j] * msk[j] * sc[j * SC_S + kk];
            cw[kk] = c;
        }
        __syncthreads();

        // ---- line embedding out: sum_k cw[k]*v[k][d], zero empty lines
        if (tid < DPH) {
            float acc = 0.f;
            for (int kk = 0; kk < WPL; ++kk)
                acc += cw[kk] * qkv[(2 * WPL + kk) * QKV_S + tid];
            line_e[line * AD + h * DPH + tid] = acc * mls;
        }
        __syncthreads();   // before next head overwrites qkv/sc
    }
}

// ---------------------------------------------------------------------------
// Kernel 2: line-level projections.  line_e[2048,400] @ {lq,lk,lv}[400,400]
// + bias, elu.  Output layout [doc][head][line][dph].
// Grid: 64 row-chunks x 4 col-chunks = 256 blocks, 256 threads.
// ---------------------------------------------------------------------------
__launch_bounds__(256)
__global__ void line_proj_kernel(const float* __restrict__ line_e,
                                 const float* __restrict__ lq_w, const float* __restrict__ lq_b,
                                 const float* __restrict__ lk_w, const float* __restrict__ lk_b,
                                 const float* __restrict__ lv_w, const float* __restrict__ lv_b,
                                 float* __restrict__ lq, float* __restrict__ lk, float* __restrict__ lv)
{
    __shared__ __align__(16) float a[32 * 404];           // 51712 B
    const int tid = threadIdx.x;
    const int rc = blockIdx.x >> 2;
    const int cc = blockIdx.x & 3;
    const int row0 = rc * 32;
    const int doc = row0 >> 7;
    const int lrow0 = row0 & 127;

    for (int idx = tid; idx < 32 * AD; idx += 256) {
        int r = idx / AD, k = idx - r * AD;
        a[r * 404 + k] = line_e[(row0 + r) * AD + k];
    }
    __syncthreads();

    for (int c0 = tid; c0 < 300; c0 += 256) {
        int c = cc * 300 + c0;
        int p = c / AD;
        int n = c - p * AD;
        const float* Wp = (p == 0) ? lq_w : (p == 1) ? lk_w : lv_w;
        const float* Bp = (p == 0) ? lq_b : (p == 1) ? lk_b : lv_b;
        float* Op = (p == 0) ? lq : (p == 1) ? lk : lv;
        float acc[32];
        #pragma unroll
        for (int i = 0; i < 32; ++i) acc[i] = 0.f;
        for (int kk = 0; kk < AD / 4; ++kk) {
            float w0 = Wp[(4 * kk + 0) * AD + n];
            float w1 = Wp[(4 * kk + 1) * AD + n];
            float w2 = Wp[(4 * kk + 2) * AD + n];
            float w3 = Wp[(4 * kk + 3) * AD + n];
            #pragma unroll
            for (int r = 0; r < 32; ++r) {
                const float4 a4 = *(const float4*)&a[r * 404 + 4 * kk];
                acc[r] += a4.x * w0 + a4.y * w1 + a4.z * w2 + a4.w * w3;
            }
        }
        float b = Bp[n];
        int hh = n / DPH, d = n - hh * DPH;
        #pragma unroll
        for (int r = 0; r < 32; ++r)
            Op[((doc * NH + hh) * LPD + lrow0 + r) * DPH + d] = elu(acc[r] + b);
    }
}

// ---------------------------------------------------------------------------
// Kernel 3: line attention + doc target attention.  Block per (doc, head).
// doc_e[h,d] = sum_k cw[k]*v[k,d],  cw[k] = sum_j tw[j]*ml[j]*w1[j][k].
// ---------------------------------------------------------------------------
__launch_bounds__(256)
__global__ void line_attn_kernel(const float* __restrict__ lq, const float* __restrict__ lk,
                                 const float* __restrict__ lv,
                                 const float* __restrict__ l_tgt, const float* __restrict__ mask_l,
                                 float* __restrict__ doc_e)
{
    __shared__ float kl[LPD * 53];      // 27136 B
    __shared__ float ql[32 * 53];       //  6784 B
    __shared__ float sc[32 * 132];      // 16896 B
    __shared__ float ts[LPD];
    __shared__ float tw[LPD];
    __shared__ float cw[LPD];
    __shared__ float ml[LPD];

    const int tid = threadIdx.x;
    const int doc = blockIdx.x >> 3;
    const int h = blockIdx.x & 7;
    const float* kbase = lk + (size_t)((doc * NH + h) * LPD) * DPH;
    const float* qbase = lq + (size_t)((doc * NH + h) * LPD) * DPH;
    const float* vbase = lv + (size_t)((doc * NH + h) * LPD) * DPH;

    if (tid < LPD) { ml[tid] = mask_l[doc * LPD + tid]; cw[tid] = 0.f; }
    for (int idx = tid; idx < LPD * DPH; idx += 256) {
        int kk = idx / DPH, d = idx - kk * DPH;
        kl[kk * 53 + d] = kbase[idx];
    }
    __syncthreads();

    // target scores + softmax (redundant reduce, broadcast LDS reads)
    if (tid < LPD) {
        float s = 0.f;
        for (int d = 0; d < DPH; ++d) s += l_tgt[h * DPH + d] * kl[tid * 53 + d];
        ts[tid] = s / SCALE - 1e7f * (1.f - ml[tid]);
    }
    __syncthreads();
    if (tid < LPD) {
        float m = -1e30f;
        for (int j = 0; j < LPD; ++j) m = fmaxf(m, ts[j]);
        float sum = 0.f;
        for (int j = 0; j < LPD; ++j) sum += expf(ts[j] - m);
        tw[tid] = expf(ts[tid] - m) / sum;
    }
    __syncthreads();

    for (int qc = 0; qc < 4; ++qc) {
        for (int idx = tid; idx < 32 * DPH; idx += 256) {
            int r = idx / DPH, d = idx - r * DPH;
            ql[r * 53 + d] = qbase[(qc * 32 + r) * DPH + d];
        }
        __syncthreads();
        {
            int j = tid >> 3, kg = tid & 7;
            for (int c = 0; c < 16; ++c) {
                int kk = kg * 16 + c;
                float s = 0.f;
                for (int d = 0; d < DPH; ++d) s += ql[j * 53 + d] * kl[kk * 53 + d];
                sc[j * 132 + kk] = s / SCALE - 1e7f * (1.f - ml[kk]);
            }
        }
        __syncthreads();
        if (tid < 32) {
            float m = -1e30f;
            for (int kk = 0; kk < LPD; ++kk) m = fmaxf(m, sc[tid * 132 + kk]);
            float sum = 0.f;
            for (int kk = 0; kk < LPD; ++kk) {
                float e = expf(sc[tid * 132 + kk] - m);
                sc[tid * 132 + kk] = e;
                sum += e;
            }
            float inv = 1.f / sum;
            for (int kk = 0; kk < LPD; ++kk) sc[tid * 132 + kk] *= inv;
        }
        __syncthreads();
        if (tid < LPD) {
            int kk = tid;
            float c = 0.f;
            for (int r = 0; r < 32; ++r) {
                int j = qc * 32 + r;
                c += tw[j] * ml[j] * sc[r * 132 + kk];
            }
            cw[kk] += c;
        }
        __syncthreads();
    }

    if (tid < DPH) {
        float acc = 0.f;
        for (int kk = 0; kk < LPD; ++kk) acc += cw[kk] * vbase[kk * DPH + tid];
        doc_e[doc * AD + h * DPH + tid] = acc;
    }
}

// ---------------------------------------------------------------------------
// Kernel 4: final FCs.  out[b, 0:70] = doc_e@fc1 + b1; out[b, 70:582] = fc2.
// ---------------------------------------------------------------------------
__global__ void logits_kernel(const float* __restrict__ doc_e,
                              const float* __restrict__ fc1_w, const float* __restrict__ fc1_b,
                              const float* __restrict__ fc2_w, const float* __restrict__ fc2_b,
                              float* __restrict__ out)
{
    int o = blockIdx.x * blockDim.x + threadIdx.x;
    if (o >= BATCH * 582) return;
    int b = o / 582, j = o - b * 582;
    const float* de = doc_e + b * AD;
    float acc;
    if (j < 70) {
        acc = fc1_b[j];
        for (int k = 0; k < AD; ++k) acc += de[k] * fc1_w[k * 70 + j];
    } else {
        int j2 = j - 70;
        acc = fc2_b[j2];
        for (int k = 0; k < AD; ++k) acc += de[k] * fc2_w[k * 512 + j2];
    }
    out[o] = acc;
}

// ---------------------------------------------------------------------------
extern "C" void kernel_launch(void* const* d_in, const int* in_sizes, int n_in,
                              void* d_out, int out_size, void* d_ws, size_t ws_size,
                              hipStream_t stream) {
    const int*   docs  = (const int*)  d_in[0];
    const float* emb   = (const float*)d_in[1];
    const float* wq_w  = (const float*)d_in[2];
    const float* wq_b  = (const float*)d_in[3];
    const float* wk_w  = (const float*)d_in[4];
    const float* wk_b  = (const float*)d_in[5];
    const float* wv_w  = (const float*)d_in[6];
    const float* wv_b  = (const float*)d_in[7];
    const float* w_tgt = (const float*)d_in[8];
    const float* lq_w  = (const float*)d_in[9];
    const float* lq_b  = (const float*)d_in[10];
    const float* lk_w  = (const float*)d_in[11];
    const float* lk_b  = (const float*)d_in[12];
    const float* lv_w  = (const float*)d_in[13];
    const float* lv_b  = (const float*)d_in[14];
    const float* l_tgt = (const float*)d_in[15];
    const float* fc1_w = (const float*)d_in[16];
    const float* fc1_b = (const float*)d_in[17];
    const float* fc2_w = (const float*)d_in[18];
    const float* fc2_b = (const float*)d_in[19];
    float* out = (float*)d_out;

    float* ws = (float*)d_ws;
    float* line_e = ws;                        // 2048*400
    float* mask_l = ws + 819200;               // 2048
    float* lq     = ws + 821248;               // 819200
    float* lk     = ws + 1640448;              // 819200
    float* lv     = ws + 2459648;              // 819200
    float* doc_e  = ws + 3278848;              // 6400

    word_kernel<<<NLINES, 320, 0, stream>>>(docs, emb, wq_w, wq_b, wk_w, wk_b,
                                            wv_w, wv_b, w_tgt, line_e, mask_l);
    line_proj_kernel<<<256, 256, 0, stream>>>(line_e, lq_w, lq_b, lk_w, lk_b,
                                              lv_w, lv_b, lq, lk, lv);
    line_attn_kernel<<<BATCH * NH, 256, 0, stream>>>(lq, lk, lv, l_tgt, mask_l, doc_e);
    logits_kernel<<<(BATCH * 582 + 255) / 256, 256, 0, stream>>>(doc_e, fc1_w, fc1_b,
                                                                 fc2_w, fc2_b, out);
}